// Round 2
// baseline (686.426 us; speedup 1.0000x reference)
//
#include <hip/hip_runtime.h>
#include <hip/hip_bf16.h>

using short8 = __attribute__((ext_vector_type(8))) short;
using f32x4  = __attribute__((ext_vector_type(4))) float;

#define DDIM 512
#define NROWS 1024
#define CCLS 100000
#define BN 128

__device__ inline unsigned int f2bf(float f) {
    unsigned int u = __float_as_uint(f);
    u += 0x7FFFu + ((u >> 16) & 1u);   // round-to-nearest-even
    return u >> 16;
}

// ---------------- kernel 1: normalize x rows -> bf16 ----------------
__global__ __launch_bounds__(256) void norm_x(const float* __restrict__ x,
                                              unsigned short* __restrict__ xn) {
    const int row = blockIdx.x;
    const int tid = threadIdx.x;
    float2 v = *(const float2*)(x + (size_t)row * DDIM + tid * 2);
    float ss = v.x * v.x + v.y * v.y;
#pragma unroll
    for (int m = 1; m < 64; m <<= 1) ss += __shfl_xor(ss, m);
    __shared__ float wsum[4];
    if ((tid & 63) == 0) wsum[tid >> 6] = ss;
    __syncthreads();
    float inv = 1.0f / sqrtf(wsum[0] + wsum[1] + wsum[2] + wsum[3]);
    unsigned int packed = f2bf(v.x * inv) | (f2bf(v.y * inv) << 16);
    ((unsigned int*)xn)[(size_t)row * (DDIM / 2) + tid] = packed;
}

// ---------------- kernel 2: fused W-norm + GEMM + exp-rowsum + target ----------------
// One block per 128-class tile. Full-K B panel staged ONCE in LDS (128 KB,
// XOR-swizzled, winv computed in-block from f32 during convert), then all
// 8 m-tiles of xn are processed against it. W read from HBM exactly once.
// 4 waves split the m-dim (32 rows each) -> A reads have zero duplication.
__global__ __launch_bounds__(256, 1) void arc_gemm(
    const unsigned short* __restrict__ xn,   // [1024][512] bf16
    const float* __restrict__ W,             // [C][512] f32
    const int* __restrict__ labels,          // [1024]
    float* __restrict__ rowsum,              // [1024] (pre-zeroed)
    float* __restrict__ tcos)                // [1024]
{
    __shared__ unsigned short lsB[BN * DDIM]; // 131072 B, swizzled
    __shared__ float linv[BN];
    __shared__ int   llab[NROWS];

    const int tid  = threadIdx.x;
    const int lane = tid & 63;
    const int wid  = tid >> 6;
    const int c0   = blockIdx.x * BN;

#pragma unroll
    for (int i = tid; i < NROWS; i += 256) llab[i] = labels[i];

    // ---- stage B: 128 classes x 512 k, f32 -> bf16, swizzled; sumsq -> winv ----
    {
        const int row = tid >> 1;       // class row in tile
        const int h   = tid & 1;        // which 256-col half
        const int c   = c0 + row;
        char* dst = (char*)lsB + row * 1024;
        const int sw  = (row & 7) << 4;
        float ss = 0.0f;
        if (c < CCLS) {
            const float4* src = (const float4*)(W + (size_t)c * DDIM + 256 * h);
#pragma unroll 8
            for (int j = 0; j < 32; ++j) {
                float4 v0 = src[2 * j];
                float4 v1 = src[2 * j + 1];
                ss += v0.x*v0.x + v0.y*v0.y + v0.z*v0.z + v0.w*v0.w
                    + v1.x*v1.x + v1.y*v1.y + v1.z*v1.z + v1.w*v1.w;
                uint4 p;
                p.x = f2bf(v0.x) | (f2bf(v0.y) << 16);
                p.y = f2bf(v0.z) | (f2bf(v0.w) << 16);
                p.z = f2bf(v1.x) | (f2bf(v1.y) << 16);
                p.w = f2bf(v1.z) | (f2bf(v1.w) << 16);
                *(uint4*)(dst + ((512 * h + 16 * j) ^ sw)) = p;
            }
        } else {
#pragma unroll 8
            for (int j = 0; j < 32; ++j)
                *(uint4*)(dst + ((512 * h + 16 * j) ^ sw)) = make_uint4(0u, 0u, 0u, 0u);
        }
        ss += __shfl_xor(ss, 1);
        if (h == 0) linv[row] = (c < CCLS && ss > 0.0f) ? (1.0f / sqrtf(ss)) : 0.0f;
    }
    __syncthreads();

    // per-lane column constants (same for every m-tile)
    float wv[8]; int colj[8], cval[8];
#pragma unroll
    for (int j = 0; j < 8; ++j) {
        int rc  = j * 16 + (lane & 15);
        colj[j] = c0 + rc;
        cval[j] = (colj[j] < CCLS) ? 1 : 0;
        wv[j]   = linv[rc];
    }

    const int q = lane >> 4;
    const unsigned short* aW =
        xn + (size_t)(wid * 32 + (lane & 15)) * DDIM + q * 8;

#pragma unroll 1
    for (int mt = 0; mt < 8; ++mt) {
        f32x4 acc[2][8];
#pragma unroll
        for (int i = 0; i < 2; ++i)
#pragma unroll
            for (int j = 0; j < 8; ++j) acc[i][j] = (f32x4)(0.0f);

        const unsigned short* aBase = aW + (size_t)mt * 128 * DDIM;

        for (int ks = 0; ks < 16; ++ks) {
            short8 af[2];
#pragma unroll
            for (int i = 0; i < 2; ++i)
                af[i] = *(const short8*)(aBase + (size_t)i * 16 * DDIM + ks * 32);
            const int kb = ks * 64 + q * 16;
            short8 bg[8];
#pragma unroll
            for (int j = 0; j < 8; ++j) {
                int rc = j * 16 + (lane & 15);
                bg[j] = *(const short8*)((const char*)lsB + rc * 1024 + (kb ^ ((rc & 7) << 4)));
            }
#pragma unroll
            for (int i = 0; i < 2; ++i)
#pragma unroll
                for (int j = 0; j < 8; ++j)
                    acc[i][j] = __builtin_amdgcn_mfma_f32_16x16x32_bf16(
                        af[i], bg[j], acc[i][j], 0, 0, 0);
        }

        // epilogue for this m-tile: cos = acc*winv; exp-sum over classes; target capture
#pragma unroll
        for (int i = 0; i < 2; ++i) {
#pragma unroll
            for (int v = 0; v < 4; ++v) {
                const int rl  = mt * 128 + wid * 32 + i * 16 + q * 4 + v;
                const int lab = llab[rl];
                float s = 0.0f;
#pragma unroll
                for (int j = 0; j < 8; ++j) {
                    float cv = acc[i][j][v] * wv[j];
                    if (cval[j]) s += __expf(64.0f * cv);
                    if (colj[j] == lab) tcos[rl] = cv;
                }
                s += __shfl_xor(s, 1);
                s += __shfl_xor(s, 2);
                s += __shfl_xor(s, 4);
                s += __shfl_xor(s, 8);
                if ((lane & 15) == 0) atomicAdd(&rowsum[rl], s);
            }
        }
    }
}

// ---------------- kernel 3: final loss ----------------
__global__ __launch_bounds__(256) void arc_final(const float* __restrict__ rowsum,
                                                 const float* __restrict__ tcos,
                                                 float* __restrict__ out) {
    const int tid = threadIdx.x;
    const float cosM = 0.87758256189037271612f;  // cos(0.5)
    const float sinM = 0.47942553860420300027f;  // sin(0.5)
    float L = 0.0f;
    for (int n = tid; n < NROWS; n += 256) {
        float tc  = tcos[n];
        float tcl = fminf(fmaxf(tc, -1.0f + 1e-7f), 1.0f - 1e-7f);
        float num = 64.0f * (tcl * cosM - sinM * sqrtf(fmaxf(0.0f, 1.0f - tcl * tcl)));
        float den = __expf(num) + rowsum[n] - __expf(64.0f * tc);
        L += num - logf(den);
    }
    __shared__ float red[256];
    red[tid] = L;
    __syncthreads();
    for (int s = 128; s > 0; s >>= 1) {
        if (tid < s) red[tid] += red[tid + s];
        __syncthreads();
    }
    if (tid == 0) out[0] = -(red[0] / (float)NROWS);
}

// ---------------- launch ----------------
extern "C" void kernel_launch(void* const* d_in, const int* in_sizes, int n_in,
                              void* d_out, int out_size, void* d_ws, size_t ws_size,
                              hipStream_t stream) {
    const float* x      = (const float*)d_in[0];
    const float* W      = (const float*)d_in[1];
    const int*   labels = (const int*)d_in[2];
    float* out = (float*)d_out;
    char*  ws  = (char*)d_ws;

    unsigned short* xn = (unsigned short*)(ws);            // 1,048,576 B
    float* rowsum      = (float*)(ws + 1048576);           // 4,096 B
    float* tcos        = (float*)(ws + 1048576 + 4096);    // 4,096 B

    hipMemsetAsync(rowsum, 0, NROWS * sizeof(float), stream);

    norm_x<<<NROWS, 256, 0, stream>>>(x, xn);

    int grid = (CCLS + BN - 1) / BN;  // 782 blocks, one class-tile each
    arc_gemm<<<grid, 256, 0, stream>>>(xn, W, labels, rowsum, tcos);

    arc_final<<<1, 256, 0, stream>>>(rowsum, tcos, out);
}

// Round 3
// 504.914 us; speedup vs baseline: 1.3595x; 1.3595x over previous
//
#include <hip/hip_runtime.h>
#include <hip/hip_bf16.h>

using short8 = __attribute__((ext_vector_type(8))) short;
using f32x4  = __attribute__((ext_vector_type(4))) float;

#define DDIM 512
#define NROWS 1024
#define CCLS 100000

__device__ inline unsigned int f2bf(float f) {
    unsigned int u = __float_as_uint(f);
    u += 0x7FFFu + ((u >> 16) & 1u);   // round-to-nearest-even
    return u >> 16;
}

// ---------------- kernel 1: normalize x rows -> bf16 ----------------
__global__ __launch_bounds__(256) void norm_x(const float* __restrict__ x,
                                              unsigned short* __restrict__ xn) {
    const int row = blockIdx.x;
    const int tid = threadIdx.x;
    float2 v = *(const float2*)(x + (size_t)row * DDIM + tid * 2);
    float ss = v.x * v.x + v.y * v.y;
#pragma unroll
    for (int m = 1; m < 64; m <<= 1) ss += __shfl_xor(ss, m);
    __shared__ float wsum[4];
    if ((tid & 63) == 0) wsum[tid >> 6] = ss;
    __syncthreads();
    float inv = 1.0f / sqrtf(wsum[0] + wsum[1] + wsum[2] + wsum[3]);
    unsigned int packed = f2bf(v.x * inv) | (f2bf(v.y * inv) << 16);
    ((unsigned int*)xn)[(size_t)row * (DDIM / 2) + tid] = packed;
}

// ---------------- kernel 2: fused W-norm + GEMM + exp-rowsum + target ----------------
// R1 structure (128x128 tile, BK=64, 4 waves 2x2, swizzled 64-col rows) plus:
//  - XCD-grouping swizzle: all 8 m-blocks of a c-tile share b%8 -> same XCD L2
//  - winv computed in-block during the staging convert (norm_w pass eliminated)
//  - double-buffered B staging, loads issued early / written late (T14)
__global__ __launch_bounds__(256, 2) void arc_gemm(
    const unsigned short* __restrict__ xn,   // [1024][512] bf16
    const float* __restrict__ W,             // [C][512] f32
    const int* __restrict__ labels,          // [1024]
    float* __restrict__ rowsum,              // [1024] (pre-zeroed)
    float* __restrict__ tcos)                // [1024]
{
    __shared__ unsigned short lsB[2][128 * 64]; // 2 x 16 KB, XOR-swizzled
    __shared__ float linv[128];
    __shared__ float lrow[128];
    __shared__ int   llab[128];

    // ---- block decode: b = g*64 + m*8 + (c&7)  ->  XCD id = c&7 ----
    const int b  = blockIdx.x;
    const int ct = (b >> 6) * 8 + (b & 7);   // c-tile 0..783
    const int mt = (b >> 3) & 7;             // m-tile 0..7
    const int c0 = ct * 128;
    if (c0 >= CCLS) return;                  // tiles 782/783: fully out of range
    const int m0 = mt * 128;

    const int tid  = threadIdx.x;
    const int lane = tid & 63;
    const int wid  = tid >> 6;
    const int wr   = wid >> 1, wc = wid & 1;

    if (tid < 128) { lrow[tid] = 0.0f; llab[tid] = labels[m0 + tid]; }

    // staging role: thread covers rows (it*16 + tid>>4), float4-chunk (tid&15)
    const int srow0 = tid >> 4;
    const int sch   = tid & 15;

    float  ss[8];
    float4 sv[8];
#pragma unroll
    for (int it = 0; it < 8; ++it) ss[it] = 0.0f;

    // ---- prologue: stage k-chunk 0 into buf0 ----
#pragma unroll
    for (int it = 0; it < 8; ++it) {
        int r = it * 16 + srow0;
        int c = c0 + r;
        sv[it] = (c < CCLS) ? *(const float4*)(W + (size_t)c * DDIM + sch * 4)
                            : make_float4(0.f, 0.f, 0.f, 0.f);
    }
#pragma unroll
    for (int it = 0; it < 8; ++it) {
        float4 v = sv[it];
        ss[it] += v.x*v.x + v.y*v.y + v.z*v.z + v.w*v.w;
        int r = it * 16 + srow0;
        uint2 p = make_uint2(f2bf(v.x) | (f2bf(v.y) << 16),
                             f2bf(v.z) | (f2bf(v.w) << 16));
        *(uint2*)((char*)lsB[0] + r * 128 + ((sch * 8) ^ ((r & 7) << 4))) = p;
    }
    __syncthreads();

    f32x4 acc[4][4];
#pragma unroll
    for (int i = 0; i < 4; ++i)
#pragma unroll
        for (int j = 0; j < 4; ++j) acc[i][j] = (f32x4)(0.0f);

    const unsigned short* aBase =
        xn + (size_t)(m0 + wr * 64 + (lane & 15)) * DDIM + ((lane >> 4) * 8);

    int cur = 0;
    for (int k = 0; k < 8; ++k) {
        // issue next chunk's global loads early (latency hides under MFMA)
        if (k < 7) {
#pragma unroll
            for (int it = 0; it < 8; ++it) {
                int r = it * 16 + srow0;
                int c = c0 + r;
                sv[it] = (c < CCLS)
                    ? *(const float4*)(W + (size_t)c * DDIM + (k + 1) * 64 + sch * 4)
                    : make_float4(0.f, 0.f, 0.f, 0.f);
            }
        }
        // compute on buf[cur]
#pragma unroll
        for (int ks = 0; ks < 2; ++ks) {
            short8 af[4], bg[4];
#pragma unroll
            for (int i = 0; i < 4; ++i)
                af[i] = *(const short8*)(aBase + (size_t)i * 16 * DDIM + k * 64 + ks * 32);
            const int kb = ks * 64 + (lane >> 4) * 16;
#pragma unroll
            for (int j = 0; j < 4; ++j) {
                int row = wc * 64 + j * 16 + (lane & 15);
                bg[j] = *(const short8*)((const char*)lsB[cur] + row * 128 + (kb ^ ((row & 7) << 4)));
            }
#pragma unroll
            for (int i = 0; i < 4; ++i)
#pragma unroll
                for (int j = 0; j < 4; ++j)
                    acc[i][j] = __builtin_amdgcn_mfma_f32_16x16x32_bf16(
                        af[i], bg[j], acc[i][j], 0, 0, 0);
        }
        // convert + write the prefetched chunk into the other buffer
        if (k < 7) {
#pragma unroll
            for (int it = 0; it < 8; ++it) {
                float4 v = sv[it];
                ss[it] += v.x*v.x + v.y*v.y + v.z*v.z + v.w*v.w;
                int r = it * 16 + srow0;
                uint2 p = make_uint2(f2bf(v.x) | (f2bf(v.y) << 16),
                                     f2bf(v.z) | (f2bf(v.w) << 16));
                *(uint2*)((char*)lsB[cur ^ 1] + r * 128 + ((sch * 8) ^ ((r & 7) << 4))) = p;
            }
        }
        __syncthreads();
        cur ^= 1;
    }

    // ---- per-class inverse norms (16-lane reduce of staged sumsq) ----
#pragma unroll
    for (int it = 0; it < 8; ++it) {
        float s = ss[it];
        s += __shfl_xor(s, 1);
        s += __shfl_xor(s, 2);
        s += __shfl_xor(s, 4);
        s += __shfl_xor(s, 8);
        if ((lane & 15) == 0) {
            int r = it * 16 + srow0;
            linv[r] = (s > 0.0f) ? (1.0f / sqrtf(s)) : 0.0f;
        }
    }
    __syncthreads();

    // ---- epilogue: cos = acc*winv; exp-sum; target capture ----
    float wv[4]; int colj[4], cok[4];
#pragma unroll
    for (int j = 0; j < 4; ++j) {
        int rc  = wc * 64 + j * 16 + (lane & 15);
        colj[j] = c0 + rc;
        cok[j]  = (colj[j] < CCLS) ? 1 : 0;
        wv[j]   = linv[rc];
    }
#pragma unroll
    for (int i = 0; i < 4; ++i) {
#pragma unroll
        for (int v = 0; v < 4; ++v) {
            const int rl  = wr * 64 + i * 16 + (lane >> 4) * 4 + v;
            const int lab = llab[rl];
            float s = 0.0f;
#pragma unroll
            for (int j = 0; j < 4; ++j) {
                float cv = acc[i][j][v] * wv[j];
                if (cok[j]) s += __expf(64.0f * cv);
                if (colj[j] == lab) tcos[m0 + rl] = cv;
            }
            s += __shfl_xor(s, 1);
            s += __shfl_xor(s, 2);
            s += __shfl_xor(s, 4);
            s += __shfl_xor(s, 8);
            if ((lane & 15) == 0) atomicAdd(&lrow[rl], s);
        }
    }
    __syncthreads();
    if (tid < 128) atomicAdd(&rowsum[m0 + tid], lrow[tid]);
}

// ---------------- kernel 3: final loss ----------------
__global__ __launch_bounds__(256) void arc_final(const float* __restrict__ rowsum,
                                                 const float* __restrict__ tcos,
                                                 float* __restrict__ out) {
    const int tid = threadIdx.x;
    const float cosM = 0.87758256189037271612f;  // cos(0.5)
    const float sinM = 0.47942553860420300027f;  // sin(0.5)
    float L = 0.0f;
    for (int n = tid; n < NROWS; n += 256) {
        float tc  = tcos[n];
        float tcl = fminf(fmaxf(tc, -1.0f + 1e-7f), 1.0f - 1e-7f);
        float num = 64.0f * (tcl * cosM - sinM * sqrtf(fmaxf(0.0f, 1.0f - tcl * tcl)));
        float den = __expf(num) + rowsum[n] - __expf(64.0f * tc);
        L += num - logf(den);
    }
    __shared__ float red[256];
    red[tid] = L;
    __syncthreads();
    for (int s = 128; s > 0; s >>= 1) {
        if (tid < s) red[tid] += red[tid + s];
        __syncthreads();
    }
    if (tid == 0) out[0] = -(red[0] / (float)NROWS);
}

// ---------------- launch ----------------
extern "C" void kernel_launch(void* const* d_in, const int* in_sizes, int n_in,
                              void* d_out, int out_size, void* d_ws, size_t ws_size,
                              hipStream_t stream) {
    const float* x      = (const float*)d_in[0];
    const float* W      = (const float*)d_in[1];
    const int*   labels = (const int*)d_in[2];
    float* out = (float*)d_out;
    char*  ws  = (char*)d_ws;

    unsigned short* xn = (unsigned short*)(ws);            // 1,048,576 B
    float* rowsum      = (float*)(ws + 1048576);           // 4,096 B
    float* tcos        = (float*)(ws + 1048576 + 4096);    // 4,096 B

    hipMemsetAsync(rowsum, 0, NROWS * sizeof(float), stream);

    norm_x<<<NROWS, 256, 0, stream>>>(x, xn);

    // 98 groups x (8 c-tiles x 8 m-tiles); 784 c-tiles covers 100352 >= 100000
    arc_gemm<<<98 * 64, 256, 0, stream>>>(xn, W, labels, rowsum, tcos);

    arc_final<<<1, 256, 0, stream>>>(rowsum, tcos, out);
}

// Round 5
// 472.172 us; speedup vs baseline: 1.4538x; 1.0693x over previous
//
#include <hip/hip_runtime.h>
#include <hip/hip_bf16.h>

using short8 = __attribute__((ext_vector_type(8))) short;
using f32x4  = __attribute__((ext_vector_type(4))) float;

#define DDIM 512
#define NROWS 1024
#define CCLS 100000

__device__ inline unsigned int f2bf(float f) {
    unsigned int u = __float_as_uint(f);
    u += 0x7FFFu + ((u >> 16) & 1u);   // round-to-nearest-even
    return u >> 16;
}

__device__ inline unsigned int pk2(float x, float y) {
    unsigned int r;
    asm("v_cvt_pk_bf16_f32 %0, %1, %2" : "=v"(r) : "v"(x), "v"(y));
    return r;  // low16 = bf16(x), high16 = bf16(y)
}

__device__ inline void gload_lds16(const unsigned short* g, unsigned short* l) {
    __builtin_amdgcn_global_load_lds(
        (const __attribute__((address_space(1))) void*)g,
        (__attribute__((address_space(3))) void*)l, 16, 0, 0);
}

// ---------------- kernel 1: normalize x rows -> bf16 ----------------
__global__ __launch_bounds__(256) void norm_x(const float* __restrict__ x,
                                              unsigned short* __restrict__ xn) {
    const int row = blockIdx.x;
    const int tid = threadIdx.x;
    float2 v = *(const float2*)(x + (size_t)row * DDIM + tid * 2);
    float ss = v.x * v.x + v.y * v.y;
#pragma unroll
    for (int m = 1; m < 64; m <<= 1) ss += __shfl_xor(ss, m);
    __shared__ float wsum[4];
    if ((tid & 63) == 0) wsum[tid >> 6] = ss;
    __syncthreads();
    float inv = 1.0f / sqrtf(wsum[0] + wsum[1] + wsum[2] + wsum[3]);
    unsigned int packed = f2bf(v.x * inv) | (f2bf(v.y * inv) << 16);
    ((unsigned int*)xn)[(size_t)row * (DDIM / 2) + tid] = packed;
}

// ---------------- kernel 2: fused W-norm + GEMM + exp-rowsum + target ----------------
// 128x128 tile, BK=64, 4 waves (2x2). Both operands double-buffered in LDS:
//  - A (xn, already bf16): global_load_lds DMA, linear dest + pre-swizzled
//    global source column -> swizzled layout, conflict-free ds_read_b128.
//    A reads are on lgkmcnt only -> MFMA never waits on vmcnt.
//  - B (W, f32): reg-staged (issued BEFORE the A-DMA so its vmcnt wait at the
//    convert doesn't drain the DMA), packed cvt_pk -> swizzled LDS.
//  - XCD-grouping block swizzle keeps all 8 m-blocks of a c-tile on one XCD.
//  - winv computed in-block during staging (no separate norm_w pass).
__global__ __launch_bounds__(256, 2) void arc_gemm(
    const unsigned short* __restrict__ xn,   // [1024][512] bf16
    const float* __restrict__ W,             // [C][512] f32
    const int* __restrict__ labels,          // [1024]
    float* __restrict__ rowsum,              // [1024] (pre-zeroed)
    float* __restrict__ tcos)                // [1024]
{
    __shared__ unsigned short lsA[2][8192];  // 2 x 16 KB
    __shared__ unsigned short lsB[2][8192];  // 2 x 16 KB
    __shared__ float linv[128];
    __shared__ float lrow[128];
    __shared__ int   llab[128];

    // ---- block decode: b = g*64 + m*8 + (c&7) -> XCD id = c&7 ----
    const int b  = blockIdx.x;
    const int ct = (b >> 6) * 8 + (b & 7);   // c-tile 0..783
    const int mt = (b >> 3) & 7;             // m-tile 0..7
    const int c0 = ct * 128;
    if (c0 >= CCLS) return;
    const int m0 = mt * 128;

    const int tid  = threadIdx.x;
    const int lane = tid & 63;
    const int wid  = tid >> 6;
    const int wr   = wid >> 1, wc = wid & 1;
    const int q    = lane >> 4;
    const int fr   = lane & 15;

    if (tid < 128) { lrow[tid] = 0.0f; llab[tid] = labels[m0 + tid]; }

    // ---- A-DMA lane geometry: linear LDS slot (row, c) <- global col (c ^ (row&7)) ----
    int aoff[4];
#pragma unroll
    for (int it = 0; it < 4; ++it) {
        int idx = wid * 256 + it * 64 + lane;   // 16B slot index
        int row = idx >> 3;
        int col = ((idx & 7) ^ (row & 7)) * 8;  // pre-swizzled source column (elems)
        aoff[it] = (m0 + row) * DDIM + col;
    }

    // ---- W staging geometry: thread covers rows it*16+srow0, float4 chunk sch ----
    const int srow0 = tid >> 4;
    const int sch   = tid & 15;
    int  wrow[8]; bool wok[8]; int wswz[8];
#pragma unroll
    for (int it = 0; it < 8; ++it) {
        wrow[it] = it * 16 + srow0;
        wok[it]  = (c0 + wrow[it]) < CCLS;
        wswz[it] = wrow[it] * 128 + ((sch * 8) ^ ((wrow[it] & 7) << 4));
    }

    float  ss[8];
    float4 sv[8];
#pragma unroll
    for (int it = 0; it < 8; ++it) ss[it] = 0.0f;

    auto loadW = [&](int k0) {
#pragma unroll
        for (int it = 0; it < 8; ++it)
            sv[it] = wok[it]
                ? *(const float4*)(W + (size_t)(c0 + wrow[it]) * DDIM + k0 + sch * 4)
                : make_float4(0.f, 0.f, 0.f, 0.f);
    };
    auto writeW = [&](int buf) {
#pragma unroll
        for (int it = 0; it < 8; ++it) {
            float4 v = sv[it];
            ss[it] += v.x * v.x + v.y * v.y + v.z * v.z + v.w * v.w;
            *(uint2*)((char*)lsB[buf] + wswz[it]) =
                make_uint2(pk2(v.x, v.y), pk2(v.z, v.w));
        }
    };
    auto stageA = [&](int buf, int k0) {
#pragma unroll
        for (int it = 0; it < 4; ++it)
            gload_lds16(xn + (size_t)(aoff[it] + k0),
                        &lsA[buf][wid * 2048 + it * 512]);
    };

    // ---- prologue: chunk 0 ----
    loadW(0);
    stageA(0, 0);
    writeW(0);
    __syncthreads();

    f32x4 acc[4][4];
#pragma unroll
    for (int i = 0; i < 4; ++i)
#pragma unroll
        for (int j = 0; j < 4; ++j) acc[i][j] = (f32x4)(0.0f);

    int cur = 0;
#pragma unroll 1
    for (int k = 0; k < 8; ++k) {
        if (k < 7) {
            loadW((k + 1) * 64);           // oldest vmcnt ops: W regs
            stageA(cur ^ 1, (k + 1) * 64); // newer: A DMA (drained at barrier)
        }
        // compute current chunk: LDS-only operands (lgkmcnt), no vmcnt waits
#pragma unroll
        for (int ks = 0; ks < 2; ++ks) {
            short8 af[4], bg[4];
#pragma unroll
            for (int i = 0; i < 4; ++i) {
                int row = wr * 64 + i * 16 + fr;
                af[i] = *(const short8*)((const char*)lsA[cur]
                        + row * 128 + (((ks * 4 + q) ^ (row & 7)) << 4));
            }
#pragma unroll
            for (int j = 0; j < 4; ++j) {
                int row = wc * 64 + j * 16 + fr;
                bg[j] = *(const short8*)((const char*)lsB[cur]
                        + row * 128 + ((ks * 64 + q * 16) ^ ((row & 7) << 4)));
            }
#pragma unroll
            for (int i = 0; i < 4; ++i)
#pragma unroll
                for (int j = 0; j < 4; ++j)
                    acc[i][j] = __builtin_amdgcn_mfma_f32_16x16x32_bf16(
                        af[i], bg[j], acc[i][j], 0, 0, 0);
        }
        if (k < 7) writeW(cur ^ 1);     // vmcnt wait here: W regs, not the DMA
        __syncthreads();
        cur ^= 1;
    }

    // ---- per-class inverse norms (16-lane reduce of staged sumsq) ----
#pragma unroll
    for (int it = 0; it < 8; ++it) {
        float s = ss[it];
        s += __shfl_xor(s, 1);
        s += __shfl_xor(s, 2);
        s += __shfl_xor(s, 4);
        s += __shfl_xor(s, 8);
        if ((lane & 15) == 0)
            linv[wrow[it]] = (wok[it] && s > 0.0f) ? (1.0f / sqrtf(s)) : 0.0f;
    }
    __syncthreads();

    // ---- epilogue: cos = acc*winv; exp-sum; target capture ----
    float wv[4]; int colj[4], cok[4];
#pragma unroll
    for (int j = 0; j < 4; ++j) {
        int rc  = wc * 64 + j * 16 + fr;
        colj[j] = c0 + rc;
        cok[j]  = (colj[j] < CCLS) ? 1 : 0;
        wv[j]   = linv[rc];
    }
#pragma unroll
    for (int i = 0; i < 4; ++i) {
#pragma unroll
        for (int v = 0; v < 4; ++v) {
            const int rl  = wr * 64 + i * 16 + q * 4 + v;
            const int lab = llab[rl];
            float s = 0.0f;
#pragma unroll
            for (int j = 0; j < 4; ++j) {
                float cv = acc[i][j][v] * wv[j];
                if (cok[j]) s += __expf(64.0f * cv);
                if (colj[j] == lab) tcos[m0 + rl] = cv;
            }
            s += __shfl_xor(s, 1);
            s += __shfl_xor(s, 2);
            s += __shfl_xor(s, 4);
            s += __shfl_xor(s, 8);
            if (fr == 0) atomicAdd(&lrow[rl], s);
        }
    }
    __syncthreads();
    if (tid < 128) atomicAdd(&rowsum[m0 + tid], lrow[tid]);
}

// ---------------- kernel 3: final loss ----------------
__global__ __launch_bounds__(256) void arc_final(const float* __restrict__ rowsum,
                                                 const float* __restrict__ tcos,
                                                 float* __restrict__ out) {
    const int tid = threadIdx.x;
    const float cosM = 0.87758256189037271612f;  // cos(0.5)
    const float sinM = 0.47942553860420300027f;  // sin(0.5)
    float L = 0.0f;
    for (int n = tid; n < NROWS; n += 256) {
        float tc  = tcos[n];
        float tcl = fminf(fmaxf(tc, -1.0f + 1e-7f), 1.0f - 1e-7f);
        float num = 64.0f * (tcl * cosM - sinM * sqrtf(fmaxf(0.0f, 1.0f - tcl * tcl)));
        float den = __expf(num) + rowsum[n] - __expf(64.0f * tc);
        L += num - logf(den);
    }
    __shared__ float red[256];
    red[tid] = L;
    __syncthreads();
    for (int s = 128; s > 0; s >>= 1) {
        if (tid < s) red[tid] += red[tid + s];
        __syncthreads();
    }
    if (tid == 0) out[0] = -(red[0] / (float)NROWS);
}

// ---------------- launch ----------------
extern "C" void kernel_launch(void* const* d_in, const int* in_sizes, int n_in,
                              void* d_out, int out_size, void* d_ws, size_t ws_size,
                              hipStream_t stream) {
    const float* x      = (const float*)d_in[0];
    const float* W      = (const float*)d_in[1];
    const int*   labels = (const int*)d_in[2];
    float* out = (float*)d_out;
    char*  ws  = (char*)d_ws;

    unsigned short* xn = (unsigned short*)(ws);            // 1,048,576 B
    float* rowsum      = (float*)(ws + 1048576);           // 4,096 B
    float* tcos        = (float*)(ws + 1048576 + 4096);    // 4,096 B

    (void)hipMemsetAsync(rowsum, 0, NROWS * sizeof(float), stream);

    norm_x<<<NROWS, 256, 0, stream>>>(x, xn);

    // 98 groups x (8 c-tiles x 8 m-tiles); 784 c-tiles covers 100352 >= 100000
    arc_gemm<<<98 * 64, 256, 0, stream>>>(xn, W, labels, rowsum, tcos);

    arc_final<<<1, 256, 0, stream>>>(rowsum, tcos, out);
}